// Round 11
// baseline (226.613 us; speedup 1.0000x reference)
//
#include <hip/hip_runtime.h>

#define B_ 64
#define T_ 1000
#define C_ 128
#define L_ 100
#define BLANK 127     // C-1
#define LN2F 0.69314718055994530942f

__device__ __forceinline__ float flog2(float x) { return __builtin_amdgcn_logf(x); }

// DPP controls (gfx9/CDNA)
#define DPP_ROW_SHR1   0x111
#define DPP_ROW_SHR2   0x112
#define DPP_ROW_SHR4   0x114
#define DPP_ROW_SHR8   0x118
#define DPP_WAVE_SHR1  0x138   // wave-level: lane i <- lane i-1, crosses rows

template <int CTRL>
__device__ __forceinline__ int dpp_mov(int src) {
    return __builtin_amdgcn_update_dpp(0, src, CTRL, 0xF, 0xF, false);
}

// 2 waves per batch element. Wave1 = producer: gathers per-lane label probs
// for 32 frames/phase into LDS (full MLP, no serial chain). Wave0 = consumer:
// validated f64+DPP recurrence, operands from LDS (conflict-free ds_read).
// Double-buffered phases, one __syncthreads per phase.
__global__ __launch_bounds__(128) void ctc_pc_kernel(
    const int* __restrict__ y_true,      // [B, L]
    const float* __restrict__ y_pred,    // [B, T, C]
    const int* __restrict__ in_len,      // [B]
    const int* __restrict__ lab_len,     // [B]
    float* __restrict__ out)             // [B]
{
    const int b   = blockIdx.x;
    const int tid = threadIdx.x;
    const int l   = tid & 63;
    const int wv  = tid >> 6;

    // frame slot layout: [0..63]=p1 per lane, [64..127]=p3 per lane, [128]=pb
    __shared__ float lds[2 * 32 * 132];   // 33,792 B

    const int k1 = min(2 * l, L_ - 1);
    const int k3 = min(2 * l + 1, L_ - 1);
    const int e1 = y_true[b * L_ + k1];
    const int e3 = y_true[b * L_ + k3];
    const double m1 = (k1 == 0 || e1 != y_true[b * L_ + k1 - 1]) ? 1.0 : 0.0;
    const double m3 = (e3 != y_true[b * L_ + k3 - 1]) ? 1.0 : 0.0;   // k3 >= 1

    const int Teff = min(T_, in_len[b]);
    const int N      = Teff - 1;          // steps t = 1..N
    const int P_full = N >> 5;
    const int rem    = N & 31;
    const int P      = P_full + (rem ? 1 : 0);
    const float* rowb = y_pred + (size_t)b * T_ * C_;

    double a0 = 0.0, a1 = 0.0, a2 = 0.0, a3 = 0.0;
    int E = 0;

// ---- producer: fill phase phf's buffer (frames 1+phf*32 .. +31, clamped) ----
#define FILL(phf) { \
    const int bbw_ = ((phf) & 1) * 32 * 132; \
    const int tb_  = 1 + (phf) * 32; \
    _Pragma("unroll 8") \
    for (int k_ = 0; k_ < 32; ++k_) { \
        int tf_ = min(tb_ + k_, N); \
        const float* r_ = rowb + (size_t)tf_ * C_; \
        float* q_ = &lds[bbw_ + k_ * 132]; \
        q_[l]      = r_[e1] + 1e-7f; \
        q_[64 + l] = r_[e3] + 1e-7f; \
        if (l == 0) q_[128] = r_[BLANK] + 1e-7f; \
    } }

// ---- consumer: LDS read of one frame's triple ----
#define LDF(fi_, PB, P1, P3) { const float* q_ = &lds[bb_ + (fi_) * 132]; \
    P1 = q_[l]; P3 = q_[64 + l]; PB = q_[128]; }

#define STEP(PB, P1, P3) { \
    int slo_ = dpp_mov<DPP_WAVE_SHR1>(__double2loint(a3)); \
    int shi_ = dpp_mov<DPP_WAVE_SHR1>(__double2hiint(a3)); \
    double pm1_ = __hiloint2double(shi_, slo_); \
    double n0_ = (a0 + pm1_) * (double)(PB); \
    double n1_ = (a1 + a0 + m1 * pm1_) * (double)(P1); \
    double n2_ = (a2 + a1) * (double)(PB); \
    double n3_ = (a3 + a2 + m3 * a1) * (double)(P3); \
    a0 = n0_; a1 = n1_; a2 = n2_; a3 = n3_; }

#define DPPMAX(u_, ctrl_) { unsigned t_ = (unsigned)dpp_mov<ctrl_>((int)(u_)); \
    u_ = max(u_, t_); }
#define RESCALE() { \
    unsigned u_ = max(max((unsigned)__double2hiint(a0), (unsigned)__double2hiint(a1)), \
                      max((unsigned)__double2hiint(a2), (unsigned)__double2hiint(a3))); \
    DPPMAX(u_, DPP_ROW_SHR1); \
    DPPMAX(u_, DPP_ROW_SHR2); \
    DPPMAX(u_, DPP_ROW_SHR4); \
    DPPMAX(u_, DPP_ROW_SHR8); \
    unsigned g_ = max(max((unsigned)__builtin_amdgcn_readlane((int)u_, 15), \
                          (unsigned)__builtin_amdgcn_readlane((int)u_, 31)), \
                      max((unsigned)__builtin_amdgcn_readlane((int)u_, 47), \
                          (unsigned)__builtin_amdgcn_readlane((int)u_, 63))); \
    int kk_ = (int)(g_ >> 20); \
    if (kk_ > 0) { \
        double f_ = __hiloint2double((2046 - kk_) << 20, 0); \
        a0 *= f_; a1 *= f_; a2 *= f_; a3 *= f_; \
        E += kk_ - 1023; } }

#define LD4A(base_) { LDF((base_),   Ab0,A10,A30); LDF((base_)+1, Ab1,A11,A31); \
                      LDF((base_)+2, Ab2,A12,A32); LDF((base_)+3, Ab3,A13,A33); }
#define LD4B(base_) { LDF((base_),   Bb0,B10,B30); LDF((base_)+1, Bb1,B11,B31); \
                      LDF((base_)+2, Bb2,B12,B32); LDF((base_)+3, Bb3,B13,B33); }
#define S4A() { STEP(Ab0,A10,A30); STEP(Ab1,A11,A31); STEP(Ab2,A12,A32); STEP(Ab3,A13,A33); }
#define S4B() { STEP(Bb0,B10,B30); STEP(Bb1,B11,B31); STEP(Bb2,B12,B32); STEP(Bb3,B13,B33); }

    if (wv == 1) {
        FILL(0);
    } else {
        // t = 0 init from global (only lane 0's values matter)
        float pb0_ = rowb[BLANK] + 1e-7f;
        float p10_ = rowb[e1]    + 1e-7f;
        a0 = (l == 0) ? (double)pb0_ : 0.0;
        a1 = (l == 0) ? (double)p10_ : 0.0;
    }
    __syncthreads();

    for (int ph = 0; ph < P; ++ph) {
        if (wv == 1) {
            if (ph + 1 < P) FILL(ph + 1);
        } else {
            const int bb_ = (ph & 1) * 32 * 132;
            if (ph < P_full) {
                float Ab0,A10,A30, Ab1,A11,A31, Ab2,A12,A32, Ab3,A13,A33;
                float Bb0,B10,B30, Bb1,B11,B31, Bb2,B12,B32, Bb3,B13,B33;
                LD4A(0);  LD4B(4);
                S4A();    LD4A(8);
                S4B();    LD4B(12);
                S4A();    LD4A(16);
                S4B();    RESCALE();
                          LD4B(20);
                S4A();    LD4A(24);
                S4B();    LD4B(28);
                S4A();
                S4B();    RESCALE();
            } else {
                for (int k_ = 0; k_ < rem; ++k_) {
                    float pb_, p1_, p3_;
                    LDF(k_, pb_, p1_, p3_);
                    STEP(pb_, p1_, p3_);
                    if (k_ == 15) RESCALE();
                }
            }
        }
        __syncthreads();
    }

    if (wv == 0) {
        const int llb = lab_len[b];
        const int pa  = 2 * llb;
        const int qa  = pa >> 2;
        double va = ((pa & 3) == 0) ? __shfl(a0, qa) : __shfl(a2, qa);
        const int pq  = 2 * llb - 1;
        const int qb  = pq >> 2;
        double vb = ((pq & 3) == 1) ? __shfl(a1, qb) : __shfl(a3, qb);
        if (l == 0) {
            double s  = va + vb;                   // true alpha * 2^-E
            int hi    = __double2hiint(s);
            int lo    = __double2loint(s);
            int ke    = (hi >> 20) & 0x7FF;
            double mant = __hiloint2double((hi & 0x000FFFFF) | (1023 << 20), lo);
            float r = flog2((float)mant) + (float)(ke - 1023 + E);
            out[b] = -r * LN2F;
        }
    }
}

extern "C" void kernel_launch(void* const* d_in, const int* in_sizes, int n_in,
                              void* d_out, int out_size, void* d_ws, size_t ws_size,
                              hipStream_t stream) {
    const int*   y_true  = (const int*)d_in[0];
    const float* y_pred  = (const float*)d_in[1];
    const int*   in_len  = (const int*)d_in[2];
    const int*   lab_len = (const int*)d_in[3];
    float*       out     = (float*)d_out;

    ctc_pc_kernel<<<B_, 128, 0, stream>>>(y_true, y_pred, in_len, lab_len, out);
}

// Round 12
// 54.588 us; speedup vs baseline: 4.1513x; 4.1513x over previous
//
#include <hip/hip_runtime.h>

#define B_ 64
#define T_ 1000
#define C_ 128
#define L_ 100
#define BLANK 127     // C-1
#define LN2F 0.69314718055994530942f
#define FPW 8         // frames per producer wave per phase
#define PH 32         // frames per phase

__device__ __forceinline__ float flog2(float x) { return __builtin_amdgcn_logf(x); }

// DPP controls (gfx9/CDNA)
#define DPP_ROW_SHR1   0x111
#define DPP_ROW_SHR2   0x112
#define DPP_ROW_SHR4   0x114
#define DPP_ROW_SHR8   0x118
#define DPP_WAVE_SHR1  0x138   // wave-level: lane i <- lane i-1, crosses rows

template <int CTRL>
__device__ __forceinline__ int dpp_mov(int src) {
    return __builtin_amdgcn_update_dpp(0, src, CTRL, 0xF, 0xF, false);
}

// 5 waves per batch element. Waves 1-4 = producers: each owns 8 frames/phase,
// issues ALL its gathers into named regs, THEN writes LDS (load-group/write-
// group split -> real MLP). Wave 0 = consumer: validated f64+DPP recurrence
// reading operand triples from LDS. Double-buffered, 1 barrier/phase.
__global__ __launch_bounds__(320) void ctc_pc_kernel(
    const int* __restrict__ y_true,      // [B, L]
    const float* __restrict__ y_pred,    // [B, T, C]
    const int* __restrict__ in_len,      // [B]
    const int* __restrict__ lab_len,     // [B]
    float* __restrict__ out)             // [B]
{
    const int b   = blockIdx.x;
    const int tid = threadIdx.x;
    const int l   = tid & 63;
    const int wv  = tid >> 6;            // 0 = consumer, 1..4 = producers

    // frame slot: [0..63]=p1 per lane, [64..127]=p3 per lane, [128]=pb
    __shared__ float lds[2 * PH * 132];  // 33,792 B

    const int k1 = min(2 * l, L_ - 1);
    const int k3 = min(2 * l + 1, L_ - 1);
    const int e1 = y_true[b * L_ + k1];
    const int e3 = y_true[b * L_ + k3];
    const double m1 = (k1 == 0 || e1 != y_true[b * L_ + k1 - 1]) ? 1.0 : 0.0;
    const double m3 = (e3 != y_true[b * L_ + k3 - 1]) ? 1.0 : 0.0;   // k3 >= 1

    const int Teff = min(T_, in_len[b]);
    const int N      = Teff - 1;         // steps t = 1..N
    const int P_full = N >> 5;
    const int rem    = N & 31;
    const int P      = P_full + (rem ? 1 : 0);
    const float* rowb = y_pred + (size_t)b * T_ * C_;

    double a0 = 0.0, a1 = 0.0, a2 = 0.0, a3 = 0.0;
    int E = 0;

    // ---- producer: fill this wave's 8 frames of phase phf ----
    auto fillw = [&](int phf) {
        const int bbw_ = (phf & 1) * PH * 132;
        const int fs_  = (wv - 1) * FPW;
        const int tb_  = 1 + phf * PH + fs_;
        float g10,g30,gb0, g11,g31,gb1, g12,g32,gb2, g13,g33,gb3,
              g14,g34,gb4, g15,g35,gb5, g16,g36,gb6, g17,g37,gb7;
        {
            const float* r_;
            int tf_;
            tf_ = min(tb_ + 0, N); r_ = rowb + (size_t)tf_ * C_;
            g10 = r_[e1] + 1e-7f; g30 = r_[e3] + 1e-7f; gb0 = r_[BLANK] + 1e-7f;
            tf_ = min(tb_ + 1, N); r_ = rowb + (size_t)tf_ * C_;
            g11 = r_[e1] + 1e-7f; g31 = r_[e3] + 1e-7f; gb1 = r_[BLANK] + 1e-7f;
            tf_ = min(tb_ + 2, N); r_ = rowb + (size_t)tf_ * C_;
            g12 = r_[e1] + 1e-7f; g32 = r_[e3] + 1e-7f; gb2 = r_[BLANK] + 1e-7f;
            tf_ = min(tb_ + 3, N); r_ = rowb + (size_t)tf_ * C_;
            g13 = r_[e1] + 1e-7f; g33 = r_[e3] + 1e-7f; gb3 = r_[BLANK] + 1e-7f;
            tf_ = min(tb_ + 4, N); r_ = rowb + (size_t)tf_ * C_;
            g14 = r_[e1] + 1e-7f; g34 = r_[e3] + 1e-7f; gb4 = r_[BLANK] + 1e-7f;
            tf_ = min(tb_ + 5, N); r_ = rowb + (size_t)tf_ * C_;
            g15 = r_[e1] + 1e-7f; g35 = r_[e3] + 1e-7f; gb5 = r_[BLANK] + 1e-7f;
            tf_ = min(tb_ + 6, N); r_ = rowb + (size_t)tf_ * C_;
            g16 = r_[e1] + 1e-7f; g36 = r_[e3] + 1e-7f; gb6 = r_[BLANK] + 1e-7f;
            tf_ = min(tb_ + 7, N); r_ = rowb + (size_t)tf_ * C_;
            g17 = r_[e1] + 1e-7f; g37 = r_[e3] + 1e-7f; gb7 = r_[BLANK] + 1e-7f;
        }
        __builtin_amdgcn_sched_barrier(0);   // keep all loads before all writes
        {
            float* q_;
            q_ = &lds[bbw_ + (fs_ + 0) * 132]; q_[l] = g10; q_[64 + l] = g30; if (l == 0) q_[128] = gb0;
            q_ = &lds[bbw_ + (fs_ + 1) * 132]; q_[l] = g11; q_[64 + l] = g31; if (l == 0) q_[128] = gb1;
            q_ = &lds[bbw_ + (fs_ + 2) * 132]; q_[l] = g12; q_[64 + l] = g32; if (l == 0) q_[128] = gb2;
            q_ = &lds[bbw_ + (fs_ + 3) * 132]; q_[l] = g13; q_[64 + l] = g33; if (l == 0) q_[128] = gb3;
            q_ = &lds[bbw_ + (fs_ + 4) * 132]; q_[l] = g14; q_[64 + l] = g34; if (l == 0) q_[128] = gb4;
            q_ = &lds[bbw_ + (fs_ + 5) * 132]; q_[l] = g15; q_[64 + l] = g35; if (l == 0) q_[128] = gb5;
            q_ = &lds[bbw_ + (fs_ + 6) * 132]; q_[l] = g16; q_[64 + l] = g36; if (l == 0) q_[128] = gb6;
            q_ = &lds[bbw_ + (fs_ + 7) * 132]; q_[l] = g17; q_[64 + l] = g37; if (l == 0) q_[128] = gb7;
        }
    };

#define LDF(fi_, PB, P1, P3) { const float* q_ = &lds[bb_ + (fi_) * 132]; \
    P1 = q_[l]; P3 = q_[64 + l]; PB = q_[128]; }

#define STEP(PB, P1, P3) { \
    int slo_ = dpp_mov<DPP_WAVE_SHR1>(__double2loint(a3)); \
    int shi_ = dpp_mov<DPP_WAVE_SHR1>(__double2hiint(a3)); \
    double pm1_ = __hiloint2double(shi_, slo_); \
    double n0_ = (a0 + pm1_) * (double)(PB); \
    double n1_ = (a1 + a0 + m1 * pm1_) * (double)(P1); \
    double n2_ = (a2 + a1) * (double)(PB); \
    double n3_ = (a3 + a2 + m3 * a1) * (double)(P3); \
    a0 = n0_; a1 = n1_; a2 = n2_; a3 = n3_; }

#define DPPMAX(u_, ctrl_) { unsigned t_ = (unsigned)dpp_mov<ctrl_>((int)(u_)); \
    u_ = max(u_, t_); }
#define RESCALE() { \
    unsigned u_ = max(max((unsigned)__double2hiint(a0), (unsigned)__double2hiint(a1)), \
                      max((unsigned)__double2hiint(a2), (unsigned)__double2hiint(a3))); \
    DPPMAX(u_, DPP_ROW_SHR1); \
    DPPMAX(u_, DPP_ROW_SHR2); \
    DPPMAX(u_, DPP_ROW_SHR4); \
    DPPMAX(u_, DPP_ROW_SHR8); \
    unsigned g_ = max(max((unsigned)__builtin_amdgcn_readlane((int)u_, 15), \
                          (unsigned)__builtin_amdgcn_readlane((int)u_, 31)), \
                      max((unsigned)__builtin_amdgcn_readlane((int)u_, 47), \
                          (unsigned)__builtin_amdgcn_readlane((int)u_, 63))); \
    int kk_ = (int)(g_ >> 20); \
    if (kk_ > 0) { \
        double f_ = __hiloint2double((2046 - kk_) << 20, 0); \
        a0 *= f_; a1 *= f_; a2 *= f_; a3 *= f_; \
        E += kk_ - 1023; } }

#define LD4A(base_) { LDF((base_),   Ab0,A10,A30); LDF((base_)+1, Ab1,A11,A31); \
                      LDF((base_)+2, Ab2,A12,A32); LDF((base_)+3, Ab3,A13,A33); }
#define LD4B(base_) { LDF((base_),   Bb0,B10,B30); LDF((base_)+1, Bb1,B11,B31); \
                      LDF((base_)+2, Bb2,B12,B32); LDF((base_)+3, Bb3,B13,B33); }
#define S4A() { STEP(Ab0,A10,A30); STEP(Ab1,A11,A31); STEP(Ab2,A12,A32); STEP(Ab3,A13,A33); }
#define S4B() { STEP(Bb0,B10,B30); STEP(Bb1,B11,B31); STEP(Bb2,B12,B32); STEP(Bb3,B13,B33); }

    if (wv >= 1) {
        fillw(0);
    } else {
        float pb0_ = rowb[BLANK] + 1e-7f;
        float p10_ = rowb[e1]    + 1e-7f;
        a0 = (l == 0) ? (double)pb0_ : 0.0;
        a1 = (l == 0) ? (double)p10_ : 0.0;
    }
    __syncthreads();

    for (int ph = 0; ph < P; ++ph) {
        if (wv >= 1) {
            if (ph + 1 < P) fillw(ph + 1);
        } else {
            const int bb_ = (ph & 1) * PH * 132;
            if (ph < P_full) {
                float Ab0,A10,A30, Ab1,A11,A31, Ab2,A12,A32, Ab3,A13,A33;
                float Bb0,B10,B30, Bb1,B11,B31, Bb2,B12,B32, Bb3,B13,B33;
                LD4A(0);  LD4B(4);
                S4A();    LD4A(8);
                S4B();    LD4B(12);
                S4A();    LD4A(16);
                S4B();    RESCALE();
                          LD4B(20);
                S4A();    LD4A(24);
                S4B();    LD4B(28);
                S4A();
                S4B();    RESCALE();
            } else {
                for (int k_ = 0; k_ < rem; ++k_) {
                    float pb_, p1_, p3_;
                    LDF(k_, pb_, p1_, p3_);
                    STEP(pb_, p1_, p3_);
                    if (k_ == 15) RESCALE();
                }
            }
        }
        __syncthreads();
    }

    if (wv == 0) {
        const int llb = lab_len[b];
        const int pa  = 2 * llb;
        const int qa  = pa >> 2;
        double va = ((pa & 3) == 0) ? __shfl(a0, qa) : __shfl(a2, qa);
        const int pq  = 2 * llb - 1;
        const int qb  = pq >> 2;
        double vb = ((pq & 3) == 1) ? __shfl(a1, qb) : __shfl(a3, qb);
        if (l == 0) {
            double s  = va + vb;                   // true alpha * 2^-E
            int hi    = __double2hiint(s);
            int lo    = __double2loint(s);
            int ke    = (hi >> 20) & 0x7FF;
            double mant = __hiloint2double((hi & 0x000FFFFF) | (1023 << 20), lo);
            float r = flog2((float)mant) + (float)(ke - 1023 + E);
            out[b] = -r * LN2F;
        }
    }
}

extern "C" void kernel_launch(void* const* d_in, const int* in_sizes, int n_in,
                              void* d_out, int out_size, void* d_ws, size_t ws_size,
                              hipStream_t stream) {
    const int*   y_true  = (const int*)d_in[0];
    const float* y_pred  = (const float*)d_in[1];
    const int*   in_len  = (const int*)d_in[2];
    const int*   lab_len = (const int*)d_in[3];
    float*       out     = (float*)d_out;

    ctc_pc_kernel<<<B_, 320, 0, stream>>>(y_true, y_pred, in_len, lab_len, out);
}